// Round 17
// baseline (202.949 us; speedup 1.0000x reference)
//
#include <hip/hip_runtime.h>
#include <cstdint>
#include <cstddef>

#define B_ 4
#define N_ 4096
#define DIN_ 128

// c = log2(e)/8 ; C2 = c^2 ; exp(dist/8) = exp2(sqrt(d2 * C2))
#define C2_ 0.0325213905f
#define NEG2C2_ (-0.0650427810f)

typedef __attribute__((ext_vector_type(8))) short short8;
typedef __attribute__((ext_vector_type(4))) float f32x4;
typedef __attribute__((ext_vector_type(4))) unsigned short us4;
typedef __attribute__((ext_vector_type(4))) unsigned int u32x4;

#if defined(__has_builtin)
#if __has_builtin(__builtin_amdgcn_exp2f)
#define EXP2(x) __builtin_amdgcn_exp2f(x)
#else
#define EXP2(x) exp2f(x)
#endif
#else
#define EXP2(x) exp2f(x)
#endif

__device__ __forceinline__ unsigned short f2bf(float f) {
    union { float f; unsigned int i; } v; v.f = f;
    unsigned int i = v.i;
    return (unsigned short)((i + 0x7FFFu + ((i >> 16) & 1u)) >> 16);
}

__device__ __forceinline__ float bf2f(unsigned short u) {
    union { unsigned int i; float f; } v;
    v.i = ((unsigned int)u) << 16;
    return v.f;
}

__device__ __forceinline__ unsigned int cvt_pk_bf16(float lo, float hi) {
    unsigned int r;
    asm("v_cvt_pk_bf16_f32 %0, %1, %2" : "=v"(r) : "v"(lo), "v"(hi));
    return r;
}

// async 16B global->LDS (no VGPR round-trip). LDS dest = wave base + lane*16.
__device__ __forceinline__ void gload16(const void* g, void* l) {
    __builtin_amdgcn_global_load_lds(
        (const __attribute__((address_space(1))) void*)g,
        (__attribute__((address_space(3))) void*)l, 16, 0, 0);
}

// ---------------- MFMA projection: x[64 rows,128] @ {Wq,Wk,Wv} -> q,k,vT ----
// (EXACT R12 kernel — passed.) grid 256 blocks, 256 thr = 4 waves x 16 rows.
__global__ __launch_bounds__(256, 2) void proj_kernel(
    const float* __restrict__ x, const float* __restrict__ Wq,
    const float* __restrict__ Wk, const float* __restrict__ Wv,
    unsigned short* __restrict__ qb, unsigned short* __restrict__ kb,
    unsigned short* __restrict__ vT, float* __restrict__ qsq,
    float* __restrict__ ksq)
{
    __shared__ __align__(16) char smem[16384 + 3 * 16384];
    char* xb = smem;

    const int t = threadIdx.x;
    const int R0 = blockIdx.x * 64;

#pragma unroll
    for (int j = 0; j < 8; ++j) {
        const int i = t + 256 * j;              // 0..2047 float4-chunks
        const int row = i >> 5, c4 = i & 31;
        const float4 v = *(const float4*)(x + (size_t)(R0 + row) * DIN_ + c4 * 4);
        uint2 p2;
        p2.x = cvt_pk_bf16(v.x, v.y);
        p2.y = cvt_pk_bf16(v.z, v.w);
        *(uint2*)(xb + ((row * 256 + c4 * 8) ^ ((row & 7) << 4))) = p2;
    }

    {
        const int c = t & 63, dg = t >> 6;
        const int sw = (c & 7) << 4;
#pragma unroll
        for (int p = 0; p < 3; ++p) {
            const float* __restrict__ Wp = (p == 0) ? Wq : ((p == 1) ? Wk : Wv);
            char* wTp = smem + 16384 + p * 16384;
            float wv[32];
#pragma unroll
            for (int d = 0; d < 32; ++d)
                wv[d] = Wp[(size_t)(dg * 32 + d) * 64 + c];
            unsigned int pk[16];
#pragma unroll
            for (int i = 0; i < 16; ++i) pk[i] = cvt_pk_bf16(wv[2 * i], wv[2 * i + 1]);
#pragma unroll
            for (int q16 = 0; q16 < 4; ++q16)
                *(uint4*)(wTp + ((c * 256 + dg * 64 + q16 * 16) ^ sw)) =
                    *(const uint4*)&pk[q16 * 4];
        }
    }
    __syncthreads();

    const int w = t >> 6, lane = t & 63, li = lane & 15, g = lane >> 4;

    short8 xa[4];
    {
        const int ar = w * 16 + li;
        const int swa = (ar & 7) << 4;
#pragma unroll
        for (int s = 0; s < 4; ++s)
            xa[s] = *(const short8*)(xb + ((ar * 256 + s * 64 + g * 16) ^ swa));
    }

    f32x4 acc[3][4];
#pragma unroll
    for (int p = 0; p < 3; ++p)
#pragma unroll
        for (int c2 = 0; c2 < 4; ++c2) acc[p][c2] = (f32x4){0.f, 0.f, 0.f, 0.f};

#pragma unroll
    for (int p = 0; p < 3; ++p) {
        char* wTp = smem + 16384 + p * 16384;
#pragma unroll
        for (int c2 = 0; c2 < 4; ++c2) {
            const int br = c2 * 16 + li;
            const int swb = (br & 7) << 4;
#pragma unroll
            for (int s = 0; s < 4; ++s) {
                const short8 wb = *(const short8*)(wTp + ((br * 256 + s * 64 + g * 16) ^ swb));
                acc[p][c2] = __builtin_amdgcn_mfma_f32_16x16x32_bf16(xa[s], wb, acc[p][c2], 0, 0, 0);
            }
        }
    }

    const int rbase = R0 + w * 16 + g * 4;
#pragma unroll
    for (int p = 0; p < 2; ++p) {
        unsigned short* dst = (p == 0) ? qb : kb;
#pragma unroll
        for (int c2 = 0; c2 < 4; ++c2)
#pragma unroll
            for (int r = 0; r < 4; ++r)
                dst[(size_t)(rbase + r) * 64 + c2 * 16 + li] = f2bf(acc[p][c2][r]);
#pragma unroll
        for (int r = 0; r < 4; ++r) {
            float s = 0.f;
#pragma unroll
            for (int c2 = 0; c2 < 4; ++c2)
                s = fmaf(acc[p][c2][r], acc[p][c2][r], s);
            s += __shfl_xor(s, 1);
            s += __shfl_xor(s, 2);
            s += __shfl_xor(s, 4);
            s += __shfl_xor(s, 8);
            if (li == 0) {
                float* sq = (p == 0) ? qsq : ksq;
                sq[rbase + r] = s;
            }
        }
    }
    {
        const int bb = R0 >> 12;
        const int n0 = (R0 & (N_ - 1)) + w * 16 + g * 4;
#pragma unroll
        for (int c2 = 0; c2 < 4; ++c2) {
            us4 pk = { f2bf(acc[2][c2][0]), f2bf(acc[2][c2][1]),
                       f2bf(acc[2][c2][2]), f2bf(acc[2][c2][3]) };
            *(us4*)(vT + ((size_t)bb * 64 + c2 * 16 + li) * N_ + n0) = pk;
        }
    }
}

// ---------------- split-K flash attention + fused split reduction ----------
// Main loop EXACTLY R16 (passed): async gload_lds double-buffer, (256,3),
// swapped QK^T with in-register P, bf16 Opart. NEW: after writing partials,
// device-scope fence + atomic counter per (b, q-tile); the LAST of the S
// split-blocks sums the S partials (fixed s-order -> deterministic) and
// writes d_out — the separate reduce dispatch and its launch gap disappear.
__global__ __launch_bounds__(256, 3) void attn_kernel(
    const unsigned short* __restrict__ qb, const unsigned short* __restrict__ kb,
    const unsigned short* __restrict__ vT, const float* __restrict__ qsq,
    const float* __restrict__ ksq, unsigned short* __restrict__ Opart,
    float* __restrict__ Lpart, float* __restrict__ out, int* __restrict__ cnt,
    int ktn, int S)
{
    __shared__ __align__(16) char smem[32768 + 512];
    // [0,16K): K bufs 2 x [64 k][64 d] bf16, XOR-swizzled rows (linear-staged)
    // [16K,32K): V bufs 2 x [64 e][64 k] bf16, XOR-swizzled rows
    // [32K,+512): ksql 2 x 64 f32, pre-scaled by C2
    float* ksql = (float*)(smem + 32768);
    __shared__ int lastFlag;

    const int t = threadIdx.x;
    const int w = t >> 6, lane = t & 63, li = lane & 15, g = lane >> 4;
    const int b = blockIdx.y, sp = blockIdx.z;
    const int q0 = blockIdx.x * 128;
    const int kt0 = sp * ktn;

    const size_t qbase = ((size_t)b * N_ + q0 + w * 32) * 64;
    short8 qa[2][2];
    float qsc[2];
#pragma unroll
    for (int h = 0; h < 2; ++h) {
        qa[h][0] = *(const short8*)(qb + qbase + (size_t)(h * 16 + li) * 64 + g * 8);
        qa[h][1] = *(const short8*)(qb + qbase + (size_t)(h * 16 + li) * 64 + 32 + g * 8);
        qsc[h] = qsq[(size_t)b * N_ + q0 + w * 32 + h * 16 + li] * C2_;
    }

    f32x4 oa[2][4];
    float lsum[2];
#pragma unroll
    for (int h = 0; h < 2; ++h) {
        lsum[h] = 0.f;
#pragma unroll
        for (int i = 0; i < 4; ++i) oa[h][i] = (f32x4){0.f, 0.f, 0.f, 0.f};
    }

    const unsigned short* kbb = kb + (size_t)b * N_ * 64;
    const unsigned short* vtb = vT + (size_t)b * 64 * N_;
    const float* ksqb = ksq + (size_t)b * N_;

    // inverse-swizzle source lanes (rule #21): linear LDS chunk j at byte
    // j*1024 + lane*16 <-> global row = 8j + (lane>>3), col-chunk (lane&7)^(lane>>3)
    const int lrow = lane >> 3;
    const int lcc = (lane & 7) ^ lrow;

    // wave w stages chunks {2w, 2w+1} of K and V (1KB each, async, 0 VGPRs)
#define STAGE(bufi, kt)                                                          \
    {                                                                            \
        _Pragma("unroll")                                                        \
        for (int jj = 0; jj < 2; ++jj) {                                         \
            const int j = 2 * w + jj;                                            \
            const int row = 8 * j + lrow;                                        \
            gload16(kbb + (size_t)((kt) * 64 + row) * 64 + lcc * 8,              \
                    smem + (bufi) * 8192 + j * 1024);                            \
            gload16(vtb + (size_t)row * N_ + (kt) * 64 + lcc * 8,                \
                    smem + 16384 + (bufi) * 8192 + j * 1024);                    \
        }                                                                        \
    }

    const int krbase = ((li >> 2) << 3) + (li & 3);

    // ---- prologue: stage tile kt0 into buf 0 ----
    STAGE(0, kt0);
    if (t < 64) ksql[t] = ksqb[kt0 * 64 + t] * C2_;
    __syncthreads();   // drains vmcnt (async loads) + lgkmcnt

    int buf = 0;
    for (int ktl = 0; ktl < ktn; ++ktl) {
        // ---- issue next tile's async loads into buf^1 (land by the barrier) --
        const bool more = (ktl + 1 < ktn);
        float ksn = 0.f;
        if (more) {
            STAGE(buf ^ 1, kt0 + ktl + 1);
            if (t < 64) ksn = ksqb[(kt0 + ktl + 1) * 64 + t] * C2_;
        }

        char* Klds = smem + buf * 8192;
        char* Vlds = smem + 16384 + buf * 8192;
        const float* ksqlb = ksql + buf * 64;

        // ---- QK^T (swapped, K-rows permuted) + softmax -> register P ----
        u32x4 pa0[2], pa1[2];
#pragma unroll
        for (int c = 0; c < 4; ++c) {
            const int koff = ((c & 1) << 2) + ((c >> 1) << 5);   // {0,4,32,36}
            const int kr = krbase + koff;
            const int sw = (kr & 7) << 4;
            const short8 kf0 = *(const short8*)(Klds + ((kr * 128 + g * 16) ^ sw));
            const short8 kf1 = *(const short8*)(Klds + ((kr * 128 + 64 + g * 16) ^ sw));
            f32x4 s[2];
            __builtin_amdgcn_s_setprio(1);
#pragma unroll
            for (int h = 0; h < 2; ++h) {
                s[h] = (f32x4){0.f, 0.f, 0.f, 0.f};
                s[h] = __builtin_amdgcn_mfma_f32_16x16x32_bf16(kf0, qa[h][0], s[h], 0, 0, 0);
                s[h] = __builtin_amdgcn_mfma_f32_16x16x32_bf16(kf1, qa[h][1], s[h], 0, 0, 0);
            }
            __builtin_amdgcn_s_setprio(0);

            const float4 ksc = *(const float4*)(ksqlb + 8 * g + koff);
            const float kscv[4] = { ksc.x, ksc.y, ksc.z, ksc.w };
#pragma unroll
            for (int h = 0; h < 2; ++h) {
                float p[4];
#pragma unroll
                for (int r = 0; r < 4; ++r) {
                    const float d2 = fmaf(NEG2C2_, s[h][r], qsc[h] + kscv[r]);
                    const float ds = __builtin_amdgcn_sqrtf(fmaxf(d2, 0.0f));
                    p[r] = EXP2(ds);
                    lsum[h] += p[r];
                }
                const unsigned int lo = cvt_pk_bf16(p[0], p[1]);
                const unsigned int hi = cvt_pk_bf16(p[2], p[3]);
                if (c == 0)      { pa0[h].x = lo; pa0[h].y = hi; }
                else if (c == 1) { pa0[h].z = lo; pa0[h].w = hi; }
                else if (c == 2) { pa1[h].x = lo; pa1[h].y = hi; }
                else             { pa1[h].z = lo; pa1[h].w = hi; }
            }
        }

        // ---- O += P @ V ----
        short8 paf[2][2];
#pragma unroll
        for (int h = 0; h < 2; ++h) {
            paf[h][0] = __builtin_bit_cast(short8, pa0[h]);
            paf[h][1] = __builtin_bit_cast(short8, pa1[h]);
        }
        __builtin_amdgcn_s_setprio(1);
#pragma unroll
        for (int c2 = 0; c2 < 4; ++c2) {
            const int er = c2 * 16 + li;
            const int swv = (er & 7) << 4;
            const short8 vf0 = *(const short8*)(Vlds + ((er * 128 + g * 16) ^ swv));
            const short8 vf1 = *(const short8*)(Vlds + ((er * 128 + 64 + g * 16) ^ swv));
#pragma unroll
            for (int h = 0; h < 2; ++h) {
                oa[h][c2] = __builtin_amdgcn_mfma_f32_16x16x32_bf16(paf[h][0], vf0, oa[h][c2], 0, 0, 0);
                oa[h][c2] = __builtin_amdgcn_mfma_f32_16x16x32_bf16(paf[h][1], vf1, oa[h][c2], 0, 0, 0);
            }
        }
        __builtin_amdgcn_s_setprio(0);

        if (more && t < 64) ksql[(buf ^ 1) * 64 + t] = ksn;
        __syncthreads();   // readers done with buf; buf^1 fully landed (vmcnt drain)
        buf ^= 1;
    }
#undef STAGE

    // ---- write partials (unnormalized, bf16) ----
    const size_t obase = ((size_t)sp * B_ + b) * N_;
#pragma unroll
    for (int h = 0; h < 2; ++h) {
        float ls = lsum[h];
        ls += __shfl_xor(ls, 16);
        ls += __shfl_xor(ls, 32);
        if (lane < 16) Lpart[obase + q0 + w * 32 + h * 16 + li] = ls;
#pragma unroll
        for (int c2 = 0; c2 < 4; ++c2)
#pragma unroll
            for (int r = 0; r < 4; ++r)
                Opart[(obase + q0 + w * 32 + h * 16 + g * 4 + r) * 64 + c2 * 16 + li]
                    = f2bf(oa[h][c2][r]);
    }

    // ---- fused split reduction: last-arriving block sums S partials ----
    __threadfence();                       // release: partials visible device-wide
    if (t == 0) {
        const int old = atomicAdd(&cnt[b * 32 + blockIdx.x], 1);   // device scope
        lastFlag = (old == S - 1) ? 1 : 0;
    }
    __syncthreads();
    if (lastFlag) {
        __threadfence();                   // acquire: see all splits' partials
#pragma unroll
        for (int u = 0; u < 8; ++u) {
            const int idx = t + u * 256;   // 0..2047: 128 rows x 16 e4-groups
            const int row = idx >> 4;
            const int e4 = (idx & 15) << 2;
            const int rowi = q0 + row;
            float l = 0.f;
            float4 o = {0.f, 0.f, 0.f, 0.f};
            for (int s = 0; s < S; ++s) {  // fixed order -> deterministic
                const size_t pbase = ((size_t)s * B_ + b) * N_ + rowi;
                l += Lpart[pbase];
                const us4 v = *(const us4*)(Opart + pbase * 64 + e4);
                o.x += bf2f(v.x); o.y += bf2f(v.y);
                o.z += bf2f(v.z); o.w += bf2f(v.w);
            }
            const float inv = 1.0f / l;
            const float4 res = {o.x * inv, o.y * inv, o.z * inv, o.w * inv};
            *(float4*)(out + ((size_t)b * N_ + rowi) * 64 + e4) = res;
        }
    }
}

extern "C" void kernel_launch(void* const* d_in, const int* in_sizes, int n_in,
                              void* d_out, int out_size, void* d_ws, size_t ws_size,
                              hipStream_t stream) {
    (void)in_sizes; (void)n_in; (void)out_size;
    const float* x  = (const float*)d_in[0];
    const float* Wq = (const float*)d_in[1];
    const float* Wk = (const float*)d_in[2];
    const float* Wv = (const float*)d_in[3];

    char* ws = (char*)d_ws;
    const size_t MB = 1024 * 1024;
    unsigned short* qb = (unsigned short*)(ws);                 // 2 MB
    unsigned short* kb = (unsigned short*)(ws + 2 * MB);        // 2 MB
    unsigned short* vT = (unsigned short*)(ws + 4 * MB);        // 2 MB
    float* qsq = (float*)(ws + 6 * MB);                         // 64 KB
    float* ksq = (float*)(ws + 6 * MB + 65536);                 // 64 KB
    float* Lpart = (float*)(ws + 6 * MB + 262144);              // <= 512 KB
    int* cnt = (int*)(ws + 6 * MB + 786432);                    // 512 B counters
    unsigned short* Opart = (unsigned short*)(ws + 7 * MB);     // S x 2.1 MB (bf16)

    // bf16 Opart: per split B*N*64*2B = 2.097 MB
    int S;
    if (ws_size >= 7 * MB + 17 * MB)      S = 8;
    else if (ws_size >= 7 * MB + 9 * MB)  S = 4;
    else if (ws_size >= 7 * MB + 5 * MB)  S = 2;
    else                                  S = 1;

    hipMemsetAsync(cnt, 0, 128 * sizeof(int), stream);
    hipLaunchKernelGGL(proj_kernel, dim3(256), dim3(256), 0, stream,
                       x, Wq, Wk, Wv, qb, kb, vT, qsq, ksq);
    hipLaunchKernelGGL(attn_kernel, dim3(32, B_, S), dim3(256), 0, stream,
                       qb, kb, vT, qsq, ksq, Opart, Lpart, (float*)d_out, cnt,
                       64 / S, S);
}

// Round 18
// 49.814 us; speedup vs baseline: 4.0741x; 4.0741x over previous
//
#include <hip/hip_runtime.h>
#include <cstdint>
#include <cstddef>

#define B_ 4
#define N_ 4096
#define DIN_ 128

// c = log2(e)/8 ; C2 = c^2 ; exp(dist/8) = exp2(sqrt(d2 * C2))
#define C2_ 0.0325213905f
#define NEG2C2_ (-0.0650427810f)

typedef __attribute__((ext_vector_type(8))) short short8;
typedef __attribute__((ext_vector_type(4))) float f32x4;
typedef __attribute__((ext_vector_type(4))) unsigned short us4;
typedef __attribute__((ext_vector_type(4))) unsigned int u32x4;

#if defined(__has_builtin)
#if __has_builtin(__builtin_amdgcn_exp2f)
#define EXP2(x) __builtin_amdgcn_exp2f(x)
#else
#define EXP2(x) exp2f(x)
#endif
#else
#define EXP2(x) exp2f(x)
#endif

__device__ __forceinline__ unsigned short f2bf(float f) {
    union { float f; unsigned int i; } v; v.f = f;
    unsigned int i = v.i;
    return (unsigned short)((i + 0x7FFFu + ((i >> 16) & 1u)) >> 16);
}

__device__ __forceinline__ float bf2f(unsigned short u) {
    union { unsigned int i; float f; } v;
    v.i = ((unsigned int)u) << 16;
    return v.f;
}

__device__ __forceinline__ unsigned int cvt_pk_bf16(float lo, float hi) {
    unsigned int r;
    asm("v_cvt_pk_bf16_f32 %0, %1, %2" : "=v"(r) : "v"(lo), "v"(hi));
    return r;
}

// async 16B global->LDS (no VGPR round-trip). LDS dest = wave base + lane*16.
__device__ __forceinline__ void gload16(const void* g, void* l) {
    __builtin_amdgcn_global_load_lds(
        (const __attribute__((address_space(1))) void*)g,
        (__attribute__((address_space(3))) void*)l, 16, 0, 0);
}

// ---------------- MFMA projection: x[64 rows,128] @ {Wq,Wk,Wv} -> q,k,vT ----
// (EXACT R12 kernel — passed.) grid 256 blocks, 256 thr = 4 waves x 16 rows.
__global__ __launch_bounds__(256, 2) void proj_kernel(
    const float* __restrict__ x, const float* __restrict__ Wq,
    const float* __restrict__ Wk, const float* __restrict__ Wv,
    unsigned short* __restrict__ qb, unsigned short* __restrict__ kb,
    unsigned short* __restrict__ vT, float* __restrict__ qsq,
    float* __restrict__ ksq)
{
    __shared__ __align__(16) char smem[16384 + 3 * 16384];
    char* xb = smem;

    const int t = threadIdx.x;
    const int R0 = blockIdx.x * 64;

#pragma unroll
    for (int j = 0; j < 8; ++j) {
        const int i = t + 256 * j;              // 0..2047 float4-chunks
        const int row = i >> 5, c4 = i & 31;
        const float4 v = *(const float4*)(x + (size_t)(R0 + row) * DIN_ + c4 * 4);
        uint2 p2;
        p2.x = cvt_pk_bf16(v.x, v.y);
        p2.y = cvt_pk_bf16(v.z, v.w);
        *(uint2*)(xb + ((row * 256 + c4 * 8) ^ ((row & 7) << 4))) = p2;
    }

    {
        const int c = t & 63, dg = t >> 6;
        const int sw = (c & 7) << 4;
#pragma unroll
        for (int p = 0; p < 3; ++p) {
            const float* __restrict__ Wp = (p == 0) ? Wq : ((p == 1) ? Wk : Wv);
            char* wTp = smem + 16384 + p * 16384;
            float wv[32];
#pragma unroll
            for (int d = 0; d < 32; ++d)
                wv[d] = Wp[(size_t)(dg * 32 + d) * 64 + c];
            unsigned int pk[16];
#pragma unroll
            for (int i = 0; i < 16; ++i) pk[i] = cvt_pk_bf16(wv[2 * i], wv[2 * i + 1]);
#pragma unroll
            for (int q16 = 0; q16 < 4; ++q16)
                *(uint4*)(wTp + ((c * 256 + dg * 64 + q16 * 16) ^ sw)) =
                    *(const uint4*)&pk[q16 * 4];
        }
    }
    __syncthreads();

    const int w = t >> 6, lane = t & 63, li = lane & 15, g = lane >> 4;

    short8 xa[4];
    {
        const int ar = w * 16 + li;
        const int swa = (ar & 7) << 4;
#pragma unroll
        for (int s = 0; s < 4; ++s)
            xa[s] = *(const short8*)(xb + ((ar * 256 + s * 64 + g * 16) ^ swa));
    }

    f32x4 acc[3][4];
#pragma unroll
    for (int p = 0; p < 3; ++p)
#pragma unroll
        for (int c2 = 0; c2 < 4; ++c2) acc[p][c2] = (f32x4){0.f, 0.f, 0.f, 0.f};

#pragma unroll
    for (int p = 0; p < 3; ++p) {
        char* wTp = smem + 16384 + p * 16384;
#pragma unroll
        for (int c2 = 0; c2 < 4; ++c2) {
            const int br = c2 * 16 + li;
            const int swb = (br & 7) << 4;
#pragma unroll
            for (int s = 0; s < 4; ++s) {
                const short8 wb = *(const short8*)(wTp + ((br * 256 + s * 64 + g * 16) ^ swb));
                acc[p][c2] = __builtin_amdgcn_mfma_f32_16x16x32_bf16(xa[s], wb, acc[p][c2], 0, 0, 0);
            }
        }
    }

    const int rbase = R0 + w * 16 + g * 4;
#pragma unroll
    for (int p = 0; p < 2; ++p) {
        unsigned short* dst = (p == 0) ? qb : kb;
#pragma unroll
        for (int c2 = 0; c2 < 4; ++c2)
#pragma unroll
            for (int r = 0; r < 4; ++r)
                dst[(size_t)(rbase + r) * 64 + c2 * 16 + li] = f2bf(acc[p][c2][r]);
#pragma unroll
        for (int r = 0; r < 4; ++r) {
            float s = 0.f;
#pragma unroll
            for (int c2 = 0; c2 < 4; ++c2)
                s = fmaf(acc[p][c2][r], acc[p][c2][r], s);
            s += __shfl_xor(s, 1);
            s += __shfl_xor(s, 2);
            s += __shfl_xor(s, 4);
            s += __shfl_xor(s, 8);
            if (li == 0) {
                float* sq = (p == 0) ? qsq : ksq;
                sq[rbase + r] = s;
            }
        }
    }
    {
        const int bb = R0 >> 12;
        const int n0 = (R0 & (N_ - 1)) + w * 16 + g * 4;
#pragma unroll
        for (int c2 = 0; c2 < 4; ++c2) {
            us4 pk = { f2bf(acc[2][c2][0]), f2bf(acc[2][c2][1]),
                       f2bf(acc[2][c2][2]), f2bf(acc[2][c2][3]) };
            *(us4*)(vT + ((size_t)bb * 64 + c2 * 16 + li) * N_ + n0) = pk;
        }
    }
}

// ---------------- split-K flash attention, swapped QK^T, 32 q-rows/wave ----
// (EXACT R16 kernel — best passing config, attn ~37 us.) Async gload_lds
// double-buffer at __launch_bounds__(256,3) (arch-VGPR cap 85: no spill);
// one barrier/tile, vmcnt(0) drain publishes buf^1; in-register P via K-row
// permutation; bf16 Opart partials.
__global__ __launch_bounds__(256, 3) void attn_kernel(
    const unsigned short* __restrict__ qb, const unsigned short* __restrict__ kb,
    const unsigned short* __restrict__ vT, const float* __restrict__ qsq,
    const float* __restrict__ ksq, unsigned short* __restrict__ Opart,
    float* __restrict__ Lpart, int ktn)
{
    __shared__ __align__(16) char smem[32768 + 512];
    // [0,16K): K bufs 2 x [64 k][64 d] bf16, XOR-swizzled rows (linear-staged)
    // [16K,32K): V bufs 2 x [64 e][64 k] bf16, XOR-swizzled rows
    // [32K,+512): ksql 2 x 64 f32, pre-scaled by C2
    float* ksql = (float*)(smem + 32768);

    const int t = threadIdx.x;
    const int w = t >> 6, lane = t & 63, li = lane & 15, g = lane >> 4;
    const int b = blockIdx.y, sp = blockIdx.z;
    const int q0 = blockIdx.x * 128;
    const int kt0 = sp * ktn;

    const size_t qbase = ((size_t)b * N_ + q0 + w * 32) * 64;
    short8 qa[2][2];
    float qsc[2];
#pragma unroll
    for (int h = 0; h < 2; ++h) {
        qa[h][0] = *(const short8*)(qb + qbase + (size_t)(h * 16 + li) * 64 + g * 8);
        qa[h][1] = *(const short8*)(qb + qbase + (size_t)(h * 16 + li) * 64 + 32 + g * 8);
        qsc[h] = qsq[(size_t)b * N_ + q0 + w * 32 + h * 16 + li] * C2_;
    }

    f32x4 oa[2][4];
    float lsum[2];
#pragma unroll
    for (int h = 0; h < 2; ++h) {
        lsum[h] = 0.f;
#pragma unroll
        for (int i = 0; i < 4; ++i) oa[h][i] = (f32x4){0.f, 0.f, 0.f, 0.f};
    }

    const unsigned short* kbb = kb + (size_t)b * N_ * 64;
    const unsigned short* vtb = vT + (size_t)b * 64 * N_;
    const float* ksqb = ksq + (size_t)b * N_;

    // inverse-swizzle source lanes (rule #21): linear LDS chunk j at byte
    // j*1024 + lane*16 <-> global row = 8j + (lane>>3), col-chunk (lane&7)^(lane>>3)
    const int lrow = lane >> 3;
    const int lcc = (lane & 7) ^ lrow;

    // wave w stages chunks {2w, 2w+1} of K and V (1KB each, async, 0 VGPRs)
#define STAGE(bufi, kt)                                                          \
    {                                                                            \
        _Pragma("unroll")                                                        \
        for (int jj = 0; jj < 2; ++jj) {                                         \
            const int j = 2 * w + jj;                                            \
            const int row = 8 * j + lrow;                                        \
            gload16(kbb + (size_t)((kt) * 64 + row) * 64 + lcc * 8,              \
                    smem + (bufi) * 8192 + j * 1024);                            \
            gload16(vtb + (size_t)row * N_ + (kt) * 64 + lcc * 8,                \
                    smem + 16384 + (bufi) * 8192 + j * 1024);                    \
        }                                                                        \
    }

    const int krbase = ((li >> 2) << 3) + (li & 3);

    // ---- prologue: stage tile kt0 into buf 0 ----
    STAGE(0, kt0);
    if (t < 64) ksql[t] = ksqb[kt0 * 64 + t] * C2_;
    __syncthreads();   // drains vmcnt (async loads) + lgkmcnt

    int buf = 0;
    for (int ktl = 0; ktl < ktn; ++ktl) {
        // ---- issue next tile's async loads into buf^1 (land by the barrier) --
        const bool more = (ktl + 1 < ktn);
        float ksn = 0.f;
        if (more) {
            STAGE(buf ^ 1, kt0 + ktl + 1);
            if (t < 64) ksn = ksqb[(kt0 + ktl + 1) * 64 + t] * C2_;
        }

        char* Klds = smem + buf * 8192;
        char* Vlds = smem + 16384 + buf * 8192;
        const float* ksqlb = ksql + buf * 64;

        // ---- QK^T (swapped, K-rows permuted) + softmax -> register P ----
        u32x4 pa0[2], pa1[2];
#pragma unroll
        for (int c = 0; c < 4; ++c) {
            const int koff = ((c & 1) << 2) + ((c >> 1) << 5);   // {0,4,32,36}
            const int kr = krbase + koff;
            const int sw = (kr & 7) << 4;
            const short8 kf0 = *(const short8*)(Klds + ((kr * 128 + g * 16) ^ sw));
            const short8 kf1 = *(const short8*)(Klds + ((kr * 128 + 64 + g * 16) ^ sw));
            f32x4 s[2];
            __builtin_amdgcn_s_setprio(1);
#pragma unroll
            for (int h = 0; h < 2; ++h) {
                s[h] = (f32x4){0.f, 0.f, 0.f, 0.f};
                s[h] = __builtin_amdgcn_mfma_f32_16x16x32_bf16(kf0, qa[h][0], s[h], 0, 0, 0);
                s[h] = __builtin_amdgcn_mfma_f32_16x16x32_bf16(kf1, qa[h][1], s[h], 0, 0, 0);
            }
            __builtin_amdgcn_s_setprio(0);

            const float4 ksc = *(const float4*)(ksqlb + 8 * g + koff);
            const float kscv[4] = { ksc.x, ksc.y, ksc.z, ksc.w };
#pragma unroll
            for (int h = 0; h < 2; ++h) {
                float p[4];
#pragma unroll
                for (int r = 0; r < 4; ++r) {
                    const float d2 = fmaf(NEG2C2_, s[h][r], qsc[h] + kscv[r]);
                    const float ds = __builtin_amdgcn_sqrtf(fmaxf(d2, 0.0f));
                    p[r] = EXP2(ds);
                    lsum[h] += p[r];
                }
                const unsigned int lo = cvt_pk_bf16(p[0], p[1]);
                const unsigned int hi = cvt_pk_bf16(p[2], p[3]);
                if (c == 0)      { pa0[h].x = lo; pa0[h].y = hi; }
                else if (c == 1) { pa0[h].z = lo; pa0[h].w = hi; }
                else if (c == 2) { pa1[h].x = lo; pa1[h].y = hi; }
                else             { pa1[h].z = lo; pa1[h].w = hi; }
            }
        }

        // ---- O += P @ V ----
        short8 paf[2][2];
#pragma unroll
        for (int h = 0; h < 2; ++h) {
            paf[h][0] = __builtin_bit_cast(short8, pa0[h]);
            paf[h][1] = __builtin_bit_cast(short8, pa1[h]);
        }
        __builtin_amdgcn_s_setprio(1);
#pragma unroll
        for (int c2 = 0; c2 < 4; ++c2) {
            const int er = c2 * 16 + li;
            const int swv = (er & 7) << 4;
            const short8 vf0 = *(const short8*)(Vlds + ((er * 128 + g * 16) ^ swv));
            const short8 vf1 = *(const short8*)(Vlds + ((er * 128 + 64 + g * 16) ^ swv));
#pragma unroll
            for (int h = 0; h < 2; ++h) {
                oa[h][c2] = __builtin_amdgcn_mfma_f32_16x16x32_bf16(paf[h][0], vf0, oa[h][c2], 0, 0, 0);
                oa[h][c2] = __builtin_amdgcn_mfma_f32_16x16x32_bf16(paf[h][1], vf1, oa[h][c2], 0, 0, 0);
            }
        }
        __builtin_amdgcn_s_setprio(0);

        if (more && t < 64) ksql[(buf ^ 1) * 64 + t] = ksn;
        __syncthreads();   // readers done with buf; buf^1 fully landed (vmcnt drain)
        buf ^= 1;
    }
#undef STAGE

    // ---- write partials (unnormalized, bf16) ----
    const size_t obase = ((size_t)sp * B_ + b) * N_;
#pragma unroll
    for (int h = 0; h < 2; ++h) {
        float ls = lsum[h];
        ls += __shfl_xor(ls, 16);
        ls += __shfl_xor(ls, 32);
        if (lane < 16) Lpart[obase + q0 + w * 32 + h * 16 + li] = ls;
#pragma unroll
        for (int c2 = 0; c2 < 4; ++c2)
#pragma unroll
            for (int r = 0; r < 4; ++r)
                Opart[(obase + q0 + w * 32 + h * 16 + g * 4 + r) * 64 + c2 * 16 + li]
                    = f2bf(oa[h][c2][r]);
    }
}

// ---------------- combine splits + normalize (bf16 partials) ----------------
__global__ __launch_bounds__(256) void reduce_kernel(
    const unsigned short* __restrict__ Opart, const float* __restrict__ Lpart,
    float* __restrict__ out, int S)
{
    const int idx = blockIdx.x * 256 + threadIdx.x;
    const int rowg = idx >> 4;
    const int e4 = (idx & 15) << 2;
    float l = 0.f;
    float4 o = {0.f, 0.f, 0.f, 0.f};
    for (int s = 0; s < S; ++s) {
        l += Lpart[(size_t)s * (B_ * N_) + rowg];
        const us4 v = *(const us4*)(Opart + ((size_t)s * (B_ * N_) + rowg) * 64 + e4);
        o.x += bf2f(v.x); o.y += bf2f(v.y); o.z += bf2f(v.z); o.w += bf2f(v.w);
    }
    const float inv = 1.0f / l;
    const float4 res = {o.x * inv, o.y * inv, o.z * inv, o.w * inv};
    *(float4*)(out + (size_t)rowg * 64 + e4) = res;
}

extern "C" void kernel_launch(void* const* d_in, const int* in_sizes, int n_in,
                              void* d_out, int out_size, void* d_ws, size_t ws_size,
                              hipStream_t stream) {
    (void)in_sizes; (void)n_in; (void)out_size;
    const float* x  = (const float*)d_in[0];
    const float* Wq = (const float*)d_in[1];
    const float* Wk = (const float*)d_in[2];
    const float* Wv = (const float*)d_in[3];

    char* ws = (char*)d_ws;
    const size_t MB = 1024 * 1024;
    unsigned short* qb = (unsigned short*)(ws);                 // 2 MB
    unsigned short* kb = (unsigned short*)(ws + 2 * MB);        // 2 MB
    unsigned short* vT = (unsigned short*)(ws + 4 * MB);        // 2 MB
    float* qsq = (float*)(ws + 6 * MB);                         // 64 KB
    float* ksq = (float*)(ws + 6 * MB + 65536);                 // 64 KB
    float* Lpart = (float*)(ws + 6 * MB + 262144);              // <= 512 KB
    unsigned short* Opart = (unsigned short*)(ws + 7 * MB);     // S x 2.1 MB (bf16)

    // bf16 Opart: per split B*N*64*2B = 2.097 MB
    int S;
    if (ws_size >= 7 * MB + 17 * MB)      S = 8;
    else if (ws_size >= 7 * MB + 9 * MB)  S = 4;
    else if (ws_size >= 7 * MB + 5 * MB)  S = 2;
    else                                  S = 1;

    hipLaunchKernelGGL(proj_kernel, dim3(256), dim3(256), 0, stream,
                       x, Wq, Wk, Wv, qb, kb, vT, qsq, ksq);
    hipLaunchKernelGGL(attn_kernel, dim3(32, B_, S), dim3(256), 0, stream,
                       qb, kb, vT, qsq, ksq, Opart, Lpart, 64 / S);
    hipLaunchKernelGGL(reduce_kernel, dim3(1024), dim3(256), 0, stream,
                       Opart, Lpart, (float*)d_out, S);
}